// Round 9
// baseline (673.482 us; speedup 1.0000x reference)
//
#include <hip/hip_runtime.h>
#include <math.h>

// B=32768 features, K=8192 centroids, D=384. All fixed by setup_inputs.
constexpr int B = 32768;
constexpr int K = 8192;
constexpr int D = 384;
constexpr float INV_T = 1.0f / 0.07f;

// Swizzled fp8 centroid buffer: per 64-row tile t (128 tiles):
// 16-B granule c (0..23) of row r (0..63) at cbs + t*24576 + (c*64 + r)*16.
// Fragment reads are 512-B contiguous runs per half-wave. cbs is 3.1 MB ->
// L2-resident; hot tiles L1-resident. No LDS staging, barrier-free loops.
constexpr int TILE_B = 24 * 64 * 16;   // 24576

constexpr int N_CS_BLK = 512;          // centsum blocks (fused grid prefix)
constexpr int N_RM_BLK = (B / 128) * 4; // 1024 rowmax blocks (4-way col split)

typedef int    int8v    __attribute__((ext_vector_type(8)));
typedef float  floatx16 __attribute__((ext_vector_type(16)));

// ---------------------------------------------------------------------------
// Kernel 1: L2-normalize centroids -> fp8 e4m3, written in swizzled layout.
// ---------------------------------------------------------------------------
__global__ __launch_bounds__(64) void normalize_k(const float* __restrict__ cent,
                                                  unsigned char* __restrict__ cbs) {
    const int row = blockIdx.x, lane = threadIdx.x;
    const float* src = cent + (size_t)row * D;
    float4 x = {0.f, 0.f, 0.f, 0.f}, y = {0.f, 0.f, 0.f, 0.f};
    if (lane < 48) {
        x = *(const float4*)(src + lane * 8);
        y = *(const float4*)(src + lane * 8 + 4);
    }
    float ss = x.x * x.x + x.y * x.y + x.z * x.z + x.w * x.w
             + y.x * y.x + y.y * y.y + y.z * y.z + y.w * y.w;
#pragma unroll
    for (int off = 32; off > 0; off >>= 1) ss += __shfl_down(ss, off, 64);
    ss = __shfl(ss, 0, 64);
    const float inv = 1.0f / fmaxf(sqrtf(ss), 1e-12f);
    if (lane < 48) {
        int w0 = __builtin_amdgcn_cvt_pk_fp8_f32(x.x * inv, x.y * inv, 0, false);
        w0 = __builtin_amdgcn_cvt_pk_fp8_f32(x.z * inv, x.w * inv, w0, true);
        int w1 = __builtin_amdgcn_cvt_pk_fp8_f32(y.x * inv, y.y * inv, 0, false);
        w1 = __builtin_amdgcn_cvt_pk_fp8_f32(y.z * inv, y.w * inv, w1, true);
        char* dst = (char*)cbs + (size_t)(row >> 6) * TILE_B
                  + ((size_t)(lane >> 1) * 64 + (row & 63)) * 16 + (lane & 1) * 8;
        *(int2*)dst = make_int2(w0, w1);
    }
}

// Fragment: frag t (0..5), K-half h, row r -> granules 4t+2h, 4t+2h+1.
__device__ __forceinline__ int8v read_frag(const char* base, int t, int half) {
    const uint4 b0 = *(const uint4*)(base + (4 * t + 2 * half) * 1024);
    const uint4 b1 = *(const uint4*)(base + (4 * t + 2 * half + 1) * 1024);
    int8v f;
    f[0] = b0.x; f[1] = b0.y; f[2] = b0.z; f[3] = b0.w;
    f[4] = b1.x; f[5] = b1.y; f[6] = b1.z; f[7] = b1.w;
    return f;
}

// ---------------------------------------------------------------------------
// centsum block: cent_sum[j] = sum_i exp(c_j . c_i / T).
// Block = 128 j-rows x 1024-i slice (16 tiles). 64 x 8 = 512 blocks.
// Wave: 64 rows (2 A-sets) x 32 cols. (R7 shape — worked.)
// ---------------------------------------------------------------------------
__device__ __forceinline__ void centsum_body(const unsigned char* __restrict__ cbs,
                                             float* __restrict__ cent_sum, int bid) {
    const int tid = threadIdx.x, lane = tid & 63, wave = tid >> 6;
    const int wm = wave >> 1, wn = wave & 1;
    const int l31 = lane & 31, half = lane >> 5;
    const int rb = bid >> 3, ch = bid & 7;
    const int stag = (rb & 3) * 4;

    int8v afr[2][6];
#pragma unroll
    for (int s = 0; s < 2; ++s) {
        const char* abase = (const char*)cbs + (size_t)(rb * 2 + wm) * TILE_B
                          + (s * 32 + l31) * 16;
#pragma unroll
        for (int t = 0; t < 6; ++t) afr[s][t] = read_frag(abase, t, half);
    }

    float rs[2][16];
#pragma unroll
    for (int s = 0; s < 2; ++s)
#pragma unroll
        for (int r = 0; r < 16; ++r) rs[s][r] = 0.f;

#pragma unroll 2
    for (int it = 0; it < 16; ++it) {
        const int tile = ch * 16 + ((stag + it) & 15);
        const char* gb = (const char*)cbs + (size_t)tile * TILE_B
                       + (wn * 32 + l31) * 16;
        int8v bfr[6];
#pragma unroll
        for (int t = 0; t < 6; ++t) bfr[t] = read_frag(gb, t, half);
        floatx16 acc0, acc1;
#pragma unroll
        for (int r = 0; r < 16; ++r) { acc0[r] = 0.f; acc1[r] = 0.f; }
#pragma unroll
        for (int t = 0; t < 6; ++t) {
            acc0 = __builtin_amdgcn_mfma_scale_f32_32x32x64_f8f6f4(
                       afr[0][t], bfr[t], acc0, 0, 0, 0, 127, 0, 127);
            acc1 = __builtin_amdgcn_mfma_scale_f32_32x32x64_f8f6f4(
                       afr[1][t], bfr[t], acc1, 0, 0, 0, 127, 0, 127);
        }
#pragma unroll
        for (int r = 0; r < 16; ++r) {
            rs[0][r] += __expf(acc0[r] * INV_T);
            rs[1][r] += __expf(acc1[r] * INV_T);
        }
    }

#pragma unroll
    for (int s = 0; s < 2; ++s)
#pragma unroll
        for (int r = 0; r < 16; ++r) {
            float v = rs[s][r];
#pragma unroll
            for (int off = 1; off < 32; off <<= 1) v += __shfl_xor(v, off, 64);
            if (l31 == 0) {
                const int rowl = (r & 3) + 8 * (r >> 2) + 4 * half;
                atomicAdd(&cent_sum[rb * 128 + wm * 64 + s * 32 + rowl], v);
            }
        }
}

// ---------------------------------------------------------------------------
// rowmax block: 128 feature rows x 2048-col quarter (32 tiles). 1024 blocks.
// Wave = 64 rows (2 A-sets) x 32 cols. Branchy argmax: common path is one
// v_cmp + scalar skip (improvements are ~rare: E[#] ~ ln K per row).
// ---------------------------------------------------------------------------
__device__ __forceinline__ void rowmax_body(const float* __restrict__ f,
                                            const unsigned char* __restrict__ cbs,
                                            float* __restrict__ row_max4,
                                            int* __restrict__ row_arg4,
                                            int bid, float* rv, int* ri) {
    const int tid = threadIdx.x, lane = tid & 63, wave = tid >> 6;
    const int wm = wave >> 1, wn = wave & 1;
    const int l31 = lane & 31, half = lane >> 5;
    const int rb = bid >> 2, ch = bid & 3;
    const int stag = (rb & 7) * 4;

    // A: 64 feature rows per wave (2 sets of 32), fp32 -> fp8 in-register.
    int8v afr[2][6];
    const int rowbase = rb * 128 + wm * 64;
#pragma unroll
    for (int s = 0; s < 2; ++s) {
        const float* arow = f + (size_t)(rowbase + s * 32 + l31) * D;
#pragma unroll
        for (int t = 0; t < 6; ++t) {
            const float* p = arow + t * 64 + half * 32;
            int8v a;
#pragma unroll
            for (int q = 0; q < 8; ++q) {
                const float4 v = *(const float4*)(p + q * 4);
                int w = __builtin_amdgcn_cvt_pk_fp8_f32(v.x, v.y, 0, false);
                w = __builtin_amdgcn_cvt_pk_fp8_f32(v.z, v.w, w, true);
                a[q] = w;
            }
            afr[s][t] = a;
        }
    }

    float bv[2][16];
    int   bi[2][16];
#pragma unroll
    for (int s = 0; s < 2; ++s)
#pragma unroll
        for (int r = 0; r < 16; ++r) { bv[s][r] = -INFINITY; bi[s][r] = 0; }

#pragma unroll 2
    for (int it = 0; it < 32; ++it) {
        const int tile = ch * 32 + ((stag + it) & 31);
        const char* gb = (const char*)cbs + (size_t)tile * TILE_B
                       + (wn * 32 + l31) * 16;
        int8v bfr[6];
#pragma unroll
        for (int t = 0; t < 6; ++t) bfr[t] = read_frag(gb, t, half);
        floatx16 acc0, acc1;
#pragma unroll
        for (int r = 0; r < 16; ++r) { acc0[r] = 0.f; acc1[r] = 0.f; }
#pragma unroll
        for (int t = 0; t < 6; ++t) {
            acc0 = __builtin_amdgcn_mfma_scale_f32_32x32x64_f8f6f4(
                       afr[0][t], bfr[t], acc0, 0, 0, 0, 127, 0, 127);
            acc1 = __builtin_amdgcn_mfma_scale_f32_32x32x64_f8f6f4(
                       afr[1][t], bfr[t], acc1, 0, 0, 0, 127, 0, 127);
        }
        const int curCol = tile * 64 + wn * 32 + l31;
#pragma unroll
        for (int r = 0; r < 16; ++r) {
            const float v0 = acc0[r];
            if (__ballot(v0 > bv[0][r])) {
                if (v0 > bv[0][r]) { bv[0][r] = v0; bi[0][r] = curCol; }
            }
            const float v1 = acc1[r];
            if (__ballot(v1 > bv[1][r])) {
                if (v1 > bv[1][r]) { bv[1][r] = v1; bi[1][r] = curCol; }
            }
        }
    }

    // Cross-lane (col) reduce with low-index tie-break.
#pragma unroll
    for (int s = 0; s < 2; ++s)
#pragma unroll
        for (int r = 0; r < 16; ++r) {
            float v = bv[s][r]; int ix = bi[s][r];
#pragma unroll
            for (int off = 1; off < 32; off <<= 1) {
                const float ov = __shfl_xor(v, off, 64);
                const int   oi = __shfl_xor(ix, off, 64);
                if (ov > v || (ov == v && oi < ix)) { v = ov; ix = oi; }
            }
            bv[s][r] = v; bi[s][r] = ix;
        }

    // Cross-wave (wn) merge via tiny LDS.
    if (l31 == 0) {
#pragma unroll
        for (int s = 0; s < 2; ++s)
#pragma unroll
            for (int r = 0; r < 16; ++r) {
                const int row = wm * 64 + s * 32 + (r & 3) + 8 * (r >> 2) + 4 * half;
                rv[row * 2 + wn] = bv[s][r];
                ri[row * 2 + wn] = bi[s][r];
            }
    }
    __syncthreads();
    if (tid < 128) {
        const float v0 = rv[tid * 2], v1 = rv[tid * 2 + 1];
        const int   i0 = ri[tid * 2], i1 = ri[tid * 2 + 1];
        const bool take1 = (v1 > v0) || (v1 == v0 && i1 < i0);
        row_max4[(size_t)(rb * 128 + tid) * 4 + ch] = take1 ? v1 : v0;
        row_arg4[(size_t)(rb * 128 + tid) * 4 + ch] = take1 ? i1 : i0;
    }
}

// ---------------------------------------------------------------------------
// Fused kernel: blocks [0,512) = centsum, [512, 512+1024) = rowmax.
// Independent block programs sharing the L2-resident cbs; mixed pipe
// profiles per CU + backfill keep waves resident.
// ---------------------------------------------------------------------------
__global__ __launch_bounds__(256, 3) void fused_k(const float* __restrict__ f,
                                                  const unsigned char* __restrict__ cbs,
                                                  float* __restrict__ cent_sum,
                                                  float* __restrict__ row_max4,
                                                  int* __restrict__ row_arg4) {
    __shared__ float rv[256];
    __shared__ int   ri[256];
    if (blockIdx.x < N_CS_BLK)
        centsum_body(cbs, cent_sum, blockIdx.x);
    else
        rowmax_body(f, cbs, row_max4, row_arg4, blockIdx.x - N_CS_BLK, rv, ri);
}

// ---------------------------------------------------------------------------
// Kernel 4: merge 4 col-quarters; loss = mean_b log1p(cent_sum[arg]*exp(-m/T)).
// Quarters are in increasing column order: strict '>' keeps lowest index.
// ---------------------------------------------------------------------------
__global__ __launch_bounds__(256) void loss_k(const float* __restrict__ row_max4,
                                              const int* __restrict__ row_arg4,
                                              const float* __restrict__ cent_sum,
                                              float* __restrict__ out) {
    __shared__ float red[256];
    const int tid = threadIdx.x;
    float s = 0.f;
    for (int b = blockIdx.x * 256 + tid; b < B; b += gridDim.x * 256) {
        float m = row_max4[(size_t)b * 4];
        int   ix = row_arg4[(size_t)b * 4];
#pragma unroll
        for (int c = 1; c < 4; ++c) {
            const float mc = row_max4[(size_t)b * 4 + c];
            if (mc > m) { m = mc; ix = row_arg4[(size_t)b * 4 + c]; }
        }
        s += log1pf(cent_sum[ix] * expf(-m * INV_T));
    }
    red[tid] = s;
    __syncthreads();
    for (int off = 128; off > 0; off >>= 1) {
        if (tid < off) red[tid] += red[tid + off];
        __syncthreads();
    }
    if (tid == 0) atomicAdd(out, red[0] / (float)B);
}

extern "C" void kernel_launch(void* const* d_in, const int* in_sizes, int n_in,
                              void* d_out, int out_size, void* d_ws, size_t ws_size,
                              hipStream_t stream) {
    const float* features  = (const float*)d_in[0];   // [B, D] fp32
    const float* centroids = (const float*)d_in[1];   // [K, D] fp32
    float* out = (float*)d_out;

    char* ws = (char*)d_ws;
    unsigned char* cbs = (unsigned char*)ws;                  // swizzled fp8, 3.1 MB
    float* cent_sum = (float*)(ws + (size_t)(K / 64) * TILE_B);
    float* row_max4 = cent_sum + K;                           // [B][4]
    int*   row_arg4 = (int*)(row_max4 + 4 * (size_t)B);       // [B][4]

    hipMemsetAsync(cent_sum, 0, K * sizeof(float), stream);
    hipMemsetAsync(out, 0, sizeof(float), stream);
    normalize_k<<<K, 64, 0, stream>>>(centroids, cbs);
    fused_k<<<N_CS_BLK + N_RM_BLK, 256, 0, stream>>>(features, cbs, cent_sum,
                                                     row_max4, row_arg4);
    loss_k<<<64, 256, 0, stream>>>(row_max4, row_arg4, cent_sum, out);
}

// Round 10
// 236.908 us; speedup vs baseline: 2.8428x; 2.8428x over previous
//
#include <hip/hip_runtime.h>
#include <math.h>

// B=32768 features, K=8192 centroids, D=384. All fixed by setup_inputs.
constexpr int B = 32768;
constexpr int K = 8192;
constexpr int D = 384;
constexpr float INV_T = 1.0f / 0.07f;

// Swizzled fp8 centroid buffer: per 64-row tile t (128 tiles):
// 16-B granule c (0..23) of row r (0..63) at cbs + t*24576 + (c*64 + r)*16.
// Fragment reads are 512-B contiguous runs per half-wave. cbs is 3.1 MB ->
// L2-resident; hot tiles L1-resident. No LDS staging, barrier-free loops.
constexpr int TILE_B = 24 * 64 * 16;   // 24576

typedef int    int8v    __attribute__((ext_vector_type(8)));
typedef float  floatx16 __attribute__((ext_vector_type(16)));

// ---------------------------------------------------------------------------
// Kernel 1: L2-normalize centroids -> fp8 e4m3 in swizzled layout.
// Also zero-initializes cent_sum (lane 0 per row) and out (block 0), so no
// separate memset dispatches are needed (stream order guarantees visibility).
// ---------------------------------------------------------------------------
__global__ __launch_bounds__(64) void normalize_k(const float* __restrict__ cent,
                                                  unsigned char* __restrict__ cbs,
                                                  float* __restrict__ cent_sum,
                                                  float* __restrict__ out) {
    const int row = blockIdx.x, lane = threadIdx.x;
    if (lane == 0) cent_sum[row] = 0.f;
    if (row == 0 && lane == 63) out[0] = 0.f;
    const float* src = cent + (size_t)row * D;
    float4 x = {0.f, 0.f, 0.f, 0.f}, y = {0.f, 0.f, 0.f, 0.f};
    if (lane < 48) {
        x = *(const float4*)(src + lane * 8);
        y = *(const float4*)(src + lane * 8 + 4);
    }
    float ss = x.x * x.x + x.y * x.y + x.z * x.z + x.w * x.w
             + y.x * y.x + y.y * y.y + y.z * y.z + y.w * y.w;
#pragma unroll
    for (int off = 32; off > 0; off >>= 1) ss += __shfl_down(ss, off, 64);
    ss = __shfl(ss, 0, 64);
    const float inv = 1.0f / fmaxf(sqrtf(ss), 1e-12f);
    if (lane < 48) {
        int w0 = __builtin_amdgcn_cvt_pk_fp8_f32(x.x * inv, x.y * inv, 0, false);
        w0 = __builtin_amdgcn_cvt_pk_fp8_f32(x.z * inv, x.w * inv, w0, true);
        int w1 = __builtin_amdgcn_cvt_pk_fp8_f32(y.x * inv, y.y * inv, 0, false);
        w1 = __builtin_amdgcn_cvt_pk_fp8_f32(y.z * inv, y.w * inv, w1, true);
        char* dst = (char*)cbs + (size_t)(row >> 6) * TILE_B
                  + ((size_t)(lane >> 1) * 64 + (row & 63)) * 16 + (lane & 1) * 8;
        *(int2*)dst = make_int2(w0, w1);
    }
}

// Fragment: frag t (0..5), K-half h, row r -> granules 4t+2h, 4t+2h+1.
__device__ __forceinline__ int8v read_frag(const char* base, int t, int half) {
    const uint4 b0 = *(const uint4*)(base + (4 * t + 2 * half) * 1024);
    const uint4 b1 = *(const uint4*)(base + (4 * t + 2 * half + 1) * 1024);
    int8v f;
    f[0] = b0.x; f[1] = b0.y; f[2] = b0.z; f[3] = b0.w;
    f[4] = b1.x; f[5] = b1.y; f[6] = b1.z; f[7] = b1.w;
    return f;
}

// ---------------------------------------------------------------------------
// Kernel 2: cent_sum[j] = sum_i exp(c_j . c_i / T).
// Block = 128 j-rows x 1024-i slice (16 tiles). Grid 64 x 8 = 512.
// Wave: 64 rows (2 A-sets) x 32 cols. Zero-extra-register software pipeline:
// after the two MFMAs on bfr[t], the slot is reloaded from the NEXT tile, so
// loads stream during the MFMA + exp phases.
// ---------------------------------------------------------------------------
__global__ __launch_bounds__(256, 2) void centsum_k(const unsigned char* __restrict__ cbs,
                                                    float* __restrict__ cent_sum) {
    const int tid = threadIdx.x, lane = tid & 63, wave = tid >> 6;
    const int wm = wave >> 1, wn = wave & 1;
    const int l31 = lane & 31, half = lane >> 5;
    const int rb = blockIdx.x >> 3, ch = blockIdx.x & 7;
    const int stag = (rb & 3) * 4;
    const int fragoff = (wn * 32 + l31) * 16;

    int8v afr[2][6];
#pragma unroll
    for (int s = 0; s < 2; ++s) {
        const char* abase = (const char*)cbs + (size_t)(rb * 2 + wm) * TILE_B
                          + (s * 32 + l31) * 16;
#pragma unroll
        for (int t = 0; t < 6; ++t) afr[s][t] = read_frag(abase, t, half);
    }

    float rs[2][16];
#pragma unroll
    for (int s = 0; s < 2; ++s)
#pragma unroll
        for (int r = 0; r < 16; ++r) rs[s][r] = 0.f;

    // Pipeline prologue: load tile 0's fragments.
    int8v bfr[6];
    {
        const char* gb = (const char*)cbs
                       + (size_t)(ch * 16 + (stag & 15)) * TILE_B + fragoff;
#pragma unroll
        for (int t = 0; t < 6; ++t) bfr[t] = read_frag(gb, t, half);
    }

    for (int it = 0; it < 16; ++it) {
        const int tile = ch * 16 + ((stag + it) & 15);
        const int nit = (it + 1 < 16) ? it + 1 : it;
        const char* gn = (const char*)cbs
                       + (size_t)(ch * 16 + ((stag + nit) & 15)) * TILE_B + fragoff;
        floatx16 acc0, acc1;
#pragma unroll
        for (int r = 0; r < 16; ++r) { acc0[r] = 0.f; acc1[r] = 0.f; }
#pragma unroll
        for (int t = 0; t < 6; ++t) {
            const int8v cur = bfr[t];
            acc0 = __builtin_amdgcn_mfma_scale_f32_32x32x64_f8f6f4(
                       afr[0][t], cur, acc0, 0, 0, 0, 127, 0, 127);
            acc1 = __builtin_amdgcn_mfma_scale_f32_32x32x64_f8f6f4(
                       afr[1][t], cur, acc1, 0, 0, 0, 127, 0, 127);
            bfr[t] = read_frag(gn, t, half);   // prefetch next tile's slot t
        }
#pragma unroll
        for (int r = 0; r < 16; ++r) {
            rs[0][r] += __expf(acc0[r] * INV_T);
            rs[1][r] += __expf(acc1[r] * INV_T);
        }
    }

#pragma unroll
    for (int s = 0; s < 2; ++s)
#pragma unroll
        for (int r = 0; r < 16; ++r) {
            float v = rs[s][r];
#pragma unroll
            for (int off = 1; off < 32; off <<= 1) v += __shfl_xor(v, off, 64);
            if (l31 == 0) {
                const int rowl = (r & 3) + 8 * (r >> 2) + 4 * half;
                atomicAdd(&cent_sum[rb * 128 + wm * 64 + s * 32 + rowl], v);
            }
        }
}

// ---------------------------------------------------------------------------
// Kernel 3: per-feature-row max+argmax. Block = 128 rows x 4096-col half
// (64 tiles). Grid B/128 x 2 = 512 blocks. Wave = 64 rows (2 A-sets) x 32
// cols. Same zero-register rotate-slot pipeline; loads of tile t+1 overlap
// the MFMA chain and the argmax VALU phase of tile t.
// ---------------------------------------------------------------------------
__global__ __launch_bounds__(256, 2) void rowmax_k(const float* __restrict__ f,
                                                   const unsigned char* __restrict__ cbs,
                                                   float* __restrict__ row_max2,
                                                   int* __restrict__ row_arg2) {
    __shared__ float rv[128 * 2];
    __shared__ int   ri[128 * 2];
    const int tid = threadIdx.x, lane = tid & 63, wave = tid >> 6;
    const int wm = wave >> 1, wn = wave & 1;
    const int l31 = lane & 31, half = lane >> 5;
    const int rb = blockIdx.x >> 1, ch = blockIdx.x & 1;
    const int stag = (rb & 7) * 8;
    const int fragoff = (wn * 32 + l31) * 16;

    // A: 64 feature rows (2 sets of 32), fp32 -> fp8 in-register.
    int8v afr[2][6];
    const int rowbase = rb * 128 + wm * 64;
#pragma unroll
    for (int s = 0; s < 2; ++s) {
        const float* arow = f + (size_t)(rowbase + s * 32 + l31) * D;
#pragma unroll
        for (int t = 0; t < 6; ++t) {
            const float* p = arow + t * 64 + half * 32;
            int8v a;
#pragma unroll
            for (int q = 0; q < 8; ++q) {
                const float4 v = *(const float4*)(p + q * 4);
                int w = __builtin_amdgcn_cvt_pk_fp8_f32(v.x, v.y, 0, false);
                w = __builtin_amdgcn_cvt_pk_fp8_f32(v.z, v.w, w, true);
                a[q] = w;
            }
            afr[s][t] = a;
        }
    }

    float bv[2][16];
    int   bi[2][16];
#pragma unroll
    for (int s = 0; s < 2; ++s)
#pragma unroll
        for (int r = 0; r < 16; ++r) { bv[s][r] = -INFINITY; bi[s][r] = 0; }

    // Pipeline prologue: load tile 0's fragments.
    int8v bfr[6];
    {
        const char* gb = (const char*)cbs
                       + (size_t)(ch * 64 + (stag & 63)) * TILE_B + fragoff;
#pragma unroll
        for (int t = 0; t < 6; ++t) bfr[t] = read_frag(gb, t, half);
    }

    for (int it = 0; it < 64; ++it) {
        const int tile = ch * 64 + ((stag + it) & 63);
        const int nit = (it + 1 < 64) ? it + 1 : it;
        const char* gn = (const char*)cbs
                       + (size_t)(ch * 64 + ((stag + nit) & 63)) * TILE_B + fragoff;
        floatx16 acc0, acc1;
#pragma unroll
        for (int r = 0; r < 16; ++r) { acc0[r] = 0.f; acc1[r] = 0.f; }
#pragma unroll
        for (int t = 0; t < 6; ++t) {
            const int8v cur = bfr[t];
            acc0 = __builtin_amdgcn_mfma_scale_f32_32x32x64_f8f6f4(
                       afr[0][t], cur, acc0, 0, 0, 0, 127, 0, 127);
            acc1 = __builtin_amdgcn_mfma_scale_f32_32x32x64_f8f6f4(
                       afr[1][t], cur, acc1, 0, 0, 0, 127, 0, 127);
            bfr[t] = read_frag(gn, t, half);   // prefetch next tile's slot t
        }
        const int curCol = tile * 64 + wn * 32 + l31;
#pragma unroll
        for (int r = 0; r < 16; ++r) {
            const float v0 = acc0[r];
            if (v0 > bv[0][r]) { bv[0][r] = v0; bi[0][r] = curCol; }
            const float v1 = acc1[r];
            if (v1 > bv[1][r]) { bv[1][r] = v1; bi[1][r] = curCol; }
        }
    }

    // Cross-lane (col) reduce with low-index tie-break.
#pragma unroll
    for (int s = 0; s < 2; ++s)
#pragma unroll
        for (int r = 0; r < 16; ++r) {
            float v = bv[s][r]; int ix = bi[s][r];
#pragma unroll
            for (int off = 1; off < 32; off <<= 1) {
                const float ov = __shfl_xor(v, off, 64);
                const int   oi = __shfl_xor(ix, off, 64);
                if (ov > v || (ov == v && oi < ix)) { v = ov; ix = oi; }
            }
            bv[s][r] = v; bi[s][r] = ix;
        }

    // Cross-wave (wn) merge via tiny LDS.
    if (l31 == 0) {
#pragma unroll
        for (int s = 0; s < 2; ++s)
#pragma unroll
            for (int r = 0; r < 16; ++r) {
                const int row = wm * 64 + s * 32 + (r & 3) + 8 * (r >> 2) + 4 * half;
                rv[row * 2 + wn] = bv[s][r];
                ri[row * 2 + wn] = bi[s][r];
            }
    }
    __syncthreads();
    if (tid < 128) {
        const float v0 = rv[tid * 2], v1 = rv[tid * 2 + 1];
        const int   i0 = ri[tid * 2], i1 = ri[tid * 2 + 1];
        const bool take1 = (v1 > v0) || (v1 == v0 && i1 < i0);
        row_max2[(size_t)(rb * 128 + tid) * 2 + ch] = take1 ? v1 : v0;
        row_arg2[(size_t)(rb * 128 + tid) * 2 + ch] = take1 ? i1 : i0;
    }
}

// ---------------------------------------------------------------------------
// Kernel 4: merge col-halves, loss = mean_b log1p(cent_sum[arg]*exp(-max/T)).
// ---------------------------------------------------------------------------
__global__ __launch_bounds__(256) void loss_k(const float* __restrict__ row_max2,
                                              const int* __restrict__ row_arg2,
                                              const float* __restrict__ cent_sum,
                                              float* __restrict__ out) {
    __shared__ float red[256];
    const int tid = threadIdx.x;
    float s = 0.f;
    for (int b = blockIdx.x * 256 + tid; b < B; b += gridDim.x * 256) {
        const float m0 = row_max2[(size_t)b * 2], m1 = row_max2[(size_t)b * 2 + 1];
        // half 0 holds cols 0..4095 < half 1's: ties -> half 0.
        const bool take1 = m1 > m0;
        const float m = take1 ? m1 : m0;
        const int ix = row_arg2[(size_t)b * 2 + (take1 ? 1 : 0)];
        s += log1pf(cent_sum[ix] * expf(-m * INV_T));
    }
    red[tid] = s;
    __syncthreads();
    for (int off = 128; off > 0; off >>= 1) {
        if (tid < off) red[tid] += red[tid + off];
        __syncthreads();
    }
    if (tid == 0) atomicAdd(out, red[0] / (float)B);
}

extern "C" void kernel_launch(void* const* d_in, const int* in_sizes, int n_in,
                              void* d_out, int out_size, void* d_ws, size_t ws_size,
                              hipStream_t stream) {
    const float* features  = (const float*)d_in[0];   // [B, D] fp32
    const float* centroids = (const float*)d_in[1];   // [K, D] fp32
    float* out = (float*)d_out;

    char* ws = (char*)d_ws;
    unsigned char* cbs = (unsigned char*)ws;                  // swizzled fp8, 3.1 MB
    float* cent_sum = (float*)(ws + (size_t)(K / 64) * TILE_B);
    float* row_max2 = cent_sum + K;                           // [B][2]
    int*   row_arg2 = (int*)(row_max2 + 2 * B);               // [B][2]

    normalize_k<<<K, 64, 0, stream>>>(centroids, cbs, cent_sum, out);
    centsum_k<<<(K / 128) * 8, 256, 0, stream>>>(cbs, cent_sum);
    rowmax_k<<<(B / 128) * 2, 256, 0, stream>>>(features, cbs, row_max2, row_arg2);
    loss_k<<<64, 256, 0, stream>>>(row_max2, row_arg2, cent_sum, out);
}